// Round 5
// baseline (268.808 us; speedup 1.0000x reference)
//
#include <hip/hip_runtime.h>
#include <math.h>

#define NB 4
#define ND 96
#define NN 512
#define NA 256

static constexpr float C_TANH = 2.8853900817779268f; // 2*log2(e)
static constexpr float LOG2E  = 1.4426950408889634f;

__device__ __forceinline__ float fexp2(float x) {
#if __has_builtin(__builtin_amdgcn_exp2f)
  return __builtin_amdgcn_exp2f(x);
#else
  return exp2f(x);
#endif
}
__device__ __forceinline__ float frcp(float x) {
#if __has_builtin(__builtin_amdgcn_rcpf)
  return __builtin_amdgcn_rcpf(x);
#else
  return 1.0f / x;
#endif
}

// --- k_proj: G1[b,n,a] = C*(x.Wg1 + bg) row-major, G2 chunk-major
//     G2c[b][c][n][al] (c = a>>5, al = a&31), xt = x^T.
// Block = (b, 2 n's), thread = a. Grid 1024 -> 4 blocks/CU.
__global__ __launch_bounds__(256, 4) void k_proj(const float* __restrict__ x,
                                                 const float* __restrict__ Wg1,
                                                 const float* __restrict__ Wg2,
                                                 const float* __restrict__ bg,
                                                 float* __restrict__ G1,
                                                 float* __restrict__ G2c,
                                                 float* __restrict__ xt) {
  __shared__ float2 xsh[ND];  // xsh[d] = x[b, d, n0..n0+1]
  const int tid = threadIdx.x;
  const int b = blockIdx.x >> 8;
  const int n0 = (blockIdx.x & 255) * 2;

  if (tid < ND * 2) {
    int d = tid >> 1, j = tid & 1;
    ((float*)&xsh[d])[j] = x[(size_t)(b * ND + d) * NN + n0 + j];
  }
  __syncthreads();
  if (tid < ND) {
    float2 v = xsh[tid];
    xt[(size_t)(b * NN + n0 + 0) * ND + tid] = v.x;
    xt[(size_t)(b * NN + n0 + 1) * ND + tid] = v.y;
  }

  const int a = tid;
  const float bgv = bg[a];
  float acc1[2] = {bgv, bgv};
  float acc2[2] = {0.f, 0.f};
  const float4* __restrict__ w1p = (const float4*)(Wg1 + (size_t)a * ND);
  const float4* __restrict__ w2p = (const float4*)(Wg2 + (size_t)a * ND);

#pragma unroll 4
  for (int d4 = 0; d4 < ND / 4; ++d4) {
    float4 w1 = w1p[d4], w2 = w2p[d4];
    float w1c[4] = {w1.x, w1.y, w1.z, w1.w};
    float w2c[4] = {w2.x, w2.y, w2.z, w2.w};
#pragma unroll
    for (int dd = 0; dd < 4; ++dd) {
      float2 xq = xsh[d4 * 4 + dd];
      acc1[0] = fmaf(w1c[dd], xq.x, acc1[0]);
      acc1[1] = fmaf(w1c[dd], xq.y, acc1[1]);
      acc2[0] = fmaf(w2c[dd], xq.x, acc2[0]);
      acc2[1] = fmaf(w2c[dd], xq.y, acc2[1]);
    }
  }
  const int c = a >> 5, al = a & 31;
#pragma unroll
  for (int j = 0; j < 2; ++j) {
    G1[(size_t)(b * NN + n0 + j) * NA + a] = C_TANH * acc1[j];
    G2c[((size_t)(b * 8 + c) * NN + n0 + j) * 32 + al] = C_TANH * acc2[j];
  }
}

// --- k_main: fused pairwise-tanh attention + AV (partial over m-quarter).
// Grid 2048 = b(4) x ngroup(128 -> 4 n's) x q(4 -> 128 m's).
// 256 threads: mloc = tid&127 (m-row), nh = tid>>7 (n-pair).
// Each thread: 2 n's x its m-row x all 256 a. G2 staged via swizzled LDS.
// LDS 18KB -> 8 blocks/CU. No atomics: partial AV -> ws, reduced by k_red.
__global__ __launch_bounds__(256, 8) void k_main(const float* __restrict__ G1,
                                                 const float* __restrict__ G2c,
                                                 const float* __restrict__ xt,
                                                 const float* __restrict__ Wa_w,
                                                 const float* __restrict__ Wa_b,
                                                 const float* __restrict__ ba,
                                                 float* __restrict__ part) {
  __shared__ float4 g2sh[1024];   // 16 KB: 128 rows x 8 float4 (a-chunk = 32)
  __shared__ float attsh[512];    // [nl][mloc] 2 KB
  float* psum = (float*)g2sh;     // 8 KB alias, used after hot loop

  const int tid = threadIdx.x;
  const int bid = blockIdx.x;
  const int q  = bid & 3;
  const int ng = (bid >> 2) & 127;
  const int b  = bid >> 9;
  const int n0 = ng * 4;
  const int mloc = tid & 127;
  const int nh = tid >> 7;

  const float4* __restrict__ W4 = (const float4*)Wa_w;
  const float* __restrict__ g1r0 = G1 + (size_t)(b * NN + n0 + nh * 2) * NA;

  float acc[2] = {0.f, 0.f};
  float sw = 0.f;

  for (int c = 0; c < 8; ++c) {
    const float4* __restrict__ src =
        (const float4*)(G2c + ((size_t)(b * 8 + c) * NN + q * 128) * 32);
    __syncthreads();
#pragma unroll
    for (int k = 0; k < 4; ++k) {
      int f = k * 256 + tid;            // 0..1023, fully coalesced 16KB
      int r = f >> 3, g = f & 7;
      g2sh[r * 8 + (g ^ (r & 7))] = src[f];
    }
    __syncthreads();
#pragma unroll
    for (int k4 = 0; k4 < 8; ++k4) {
      float4 v = g2sh[mloc * 8 + (k4 ^ (mloc & 7))];
      float g2v[4] = {v.x, v.y, v.z, v.w};
      float4 wq = W4[c * 8 + k4];
      float wv[4] = {wq.x, wq.y, wq.z, wq.w};
      sw += (wv[0] + wv[1]) + (wv[2] + wv[3]);
#pragma unroll
      for (int nl = 0; nl < 2; ++nl) {
        float4 g = *(const float4*)(g1r0 + nl * NA + c * 32 + k4 * 4);
        float g1v[4] = {g.x, g.y, g.z, g.w};
#pragma unroll
        for (int j = 0; j < 4; ++j) {
          float e = fexp2(g1v[j] + g2v[j]);        // exp2(C*(g1+g2+bg))
          acc[nl] = fmaf(wv[j], frcp(1.f + e), acc[nl]);
        }
      }
    }
  }

  // att scores (each (n,m) owned by exactly one thread -> no combine)
  {
    float bias = Wa_b[0] + ba[0];
#pragma unroll
    for (int nl = 0; nl < 2; ++nl) {
      float z = (sw + bias) - 2.f * acc[nl];
      attsh[(nh * 2 + nl) * 128 + mloc] = frcp(1.f + fexp2(-LOG2E * z));
    }
  }
  __syncthreads();

  // AV over this block's 128 m-rows: wave w -> m in [w*32, w*32+32)
  const int w = tid >> 6;
  const int l = tid & 63;
  float o0[4] = {0.f, 0.f, 0.f, 0.f};
  float o1[4] = {0.f, 0.f, 0.f, 0.f};
  const float* __restrict__ xb = xt + (size_t)(b * NN + q * 128 + w * 32) * ND;
  for (int mi = 0; mi < 32; ++mi) {
    const float* xr = xb + mi * ND;
    float xv0 = xr[l];
    float xv1 = xr[64 + (l & 31)];
#pragma unroll
    for (int nl = 0; nl < 4; ++nl) {
      float av = attsh[nl * 128 + w * 32 + mi];
      o0[nl] = fmaf(av, xv0, o0[nl]);
      o1[nl] = fmaf(av, xv1, o1[nl]);
    }
  }
  __syncthreads();   // g2sh reads long done; safe to alias as psum
#pragma unroll
  for (int nl = 0; nl < 4; ++nl) {
    psum[(w * 4 + nl) * 128 + l] = o0[nl];
    if (l < 32) psum[(w * 4 + nl) * 128 + 64 + l] = o1[nl];
  }
  __syncthreads();
#pragma unroll
  for (int it = 0; it < 2; ++it) {
    int idx = it * 256 + tid;
    int nl = idx >> 7;
    int d = idx & 127;
    if (d < ND) {
      float s = (psum[(0 + nl) * 128 + d] + psum[(4 + nl) * 128 + d]) +
                (psum[(8 + nl) * 128 + d] + psum[(12 + nl) * 128 + d]);
      // part[q][b][n][d], plain store (no atomics)
      part[((size_t)(q * NB + b) * NN + n0 + nl) * ND + d] = s;
    }
  }
}

// --- k_red: out = sum of 4 m-quarter partials. 196608 elems, coalesced.
__global__ __launch_bounds__(256) void k_red(const float* __restrict__ part,
                                             float* __restrict__ out) {
  int idx = blockIdx.x * 256 + threadIdx.x;   // 0 .. 4*512*96-1
  const size_t QS = (size_t)NB * NN * ND;
  out[idx] = (part[idx] + part[QS + idx]) + (part[2 * QS + idx] + part[3 * QS + idx]);
}

extern "C" void kernel_launch(void* const* d_in, const int* in_sizes, int n_in,
                              void* d_out, int out_size, void* d_ws, size_t ws_size,
                              hipStream_t stream) {
  const float* x    = (const float*)d_in[0];
  const float* Wg1  = (const float*)d_in[1];
  const float* Wg2  = (const float*)d_in[2];
  const float* bg   = (const float*)d_in[3];
  const float* Wa_w = (const float*)d_in[4];
  const float* Wa_b = (const float*)d_in[5];
  const float* ba   = (const float*)d_in[6];
  float* out = (float*)d_out;

  float* ws   = (float*)d_ws;
  float* G1   = ws;                 // 524288 floats
  float* G2c  = ws + 524288;        // 524288 (chunk-major)
  float* xtw  = ws + 1048576;       // 196608
  float* part = ws + 1245184;       // 786432 (4 quarter-partials)  total ~8.1 MB

  hipLaunchKernelGGL(k_proj, dim3(1024), dim3(256), 0, stream,
                     x, Wg1, Wg2, bg, G1, G2c, xtw);
  hipLaunchKernelGGL(k_main, dim3(2048), dim3(256), 0, stream,
                     G1, G2c, xtw, Wa_w, Wa_b, ba, part);
  hipLaunchKernelGGL(k_red, dim3(768), dim3(256), 0, stream, part, out);
}

// Round 6
// 213.033 us; speedup vs baseline: 1.2618x; 1.2618x over previous
//
#include <hip/hip_runtime.h>
#include <math.h>

#define NB 4
#define ND 96
#define NN 512
#define NA 256

static constexpr float C_TANH = 2.8853900817779268f; // 2*log2(e)
static constexpr float LOG2E  = 1.4426950408889634f;

__device__ __forceinline__ float fexp2(float x) {
#if __has_builtin(__builtin_amdgcn_exp2f)
  return __builtin_amdgcn_exp2f(x);
#else
  return exp2f(x);
#endif
}
__device__ __forceinline__ float frcp(float x) {
#if __has_builtin(__builtin_amdgcn_rcpf)
  return __builtin_amdgcn_rcpf(x);
#else
  return 1.0f / x;
#endif
}

// --- k_proj: G1[b,n,a] = C*(x.Wg1 + bg) row-major, G2 chunk-major
//     G2c[b][c][n][al] (c = a>>5, al = a&31), xt = x^T.
// Block = (b, 2 n's), thread = a. Grid 1024 -> 4 blocks/CU.
__global__ __launch_bounds__(256, 4) void k_proj(const float* __restrict__ x,
                                                 const float* __restrict__ Wg1,
                                                 const float* __restrict__ Wg2,
                                                 const float* __restrict__ bg,
                                                 float* __restrict__ G1,
                                                 float* __restrict__ G2c,
                                                 float* __restrict__ xt) {
  __shared__ float2 xsh[ND];  // xsh[d] = x[b, d, n0..n0+1]
  const int tid = threadIdx.x;
  const int b = blockIdx.x >> 8;
  const int n0 = (blockIdx.x & 255) * 2;

  if (tid < ND * 2) {
    int d = tid >> 1, j = tid & 1;
    ((float*)&xsh[d])[j] = x[(size_t)(b * ND + d) * NN + n0 + j];
  }
  __syncthreads();
  if (tid < ND) {
    float2 v = xsh[tid];
    xt[(size_t)(b * NN + n0 + 0) * ND + tid] = v.x;
    xt[(size_t)(b * NN + n0 + 1) * ND + tid] = v.y;
  }

  const int a = tid;
  const float bgv = bg[a];
  float acc1[2] = {bgv, bgv};
  float acc2[2] = {0.f, 0.f};
  const float4* __restrict__ w1p = (const float4*)(Wg1 + (size_t)a * ND);
  const float4* __restrict__ w2p = (const float4*)(Wg2 + (size_t)a * ND);

#pragma unroll 4
  for (int d4 = 0; d4 < ND / 4; ++d4) {
    float4 w1 = w1p[d4], w2 = w2p[d4];
    float w1c[4] = {w1.x, w1.y, w1.z, w1.w};
    float w2c[4] = {w2.x, w2.y, w2.z, w2.w};
#pragma unroll
    for (int dd = 0; dd < 4; ++dd) {
      float2 xq = xsh[d4 * 4 + dd];
      acc1[0] = fmaf(w1c[dd], xq.x, acc1[0]);
      acc1[1] = fmaf(w1c[dd], xq.y, acc1[1]);
      acc2[0] = fmaf(w2c[dd], xq.x, acc2[0]);
      acc2[1] = fmaf(w2c[dd], xq.y, acc2[1]);
    }
  }
  const int c = a >> 5, al = a & 31;
#pragma unroll
  for (int j = 0; j < 2; ++j) {
    G1[(size_t)(b * NN + n0 + j) * NA + a] = C_TANH * acc1[j];
    G2c[((size_t)(b * 8 + c) * NN + n0 + j) * 32 + al] = C_TANH * acc2[j];
  }
}

// --- k_main: fused pairwise-tanh attention + AV (partial over m-quarter).
// Grid 2048: bid = q*512 + b*128 + ng  (q slowest -> concurrent blocks share
// q,b => per-XCD working set ~1.2MB, L2-resident).
// 256 threads: mloc = tid&127 (m-row), nh = tid>>7 (n-pair).
// launch_bounds(256,4): VGPR cap 128 -> NO SPILL (r3/r5 regression was
// scratch spill at the (256,8)/VGPR=32 cap: 354MB WRITE_SIZE of spill traffic).
__global__ __launch_bounds__(256, 4) void k_main(const float* __restrict__ G1,
                                                 const float* __restrict__ G2c,
                                                 const float* __restrict__ xt,
                                                 const float* __restrict__ Wa_w,
                                                 const float* __restrict__ Wa_b,
                                                 const float* __restrict__ ba,
                                                 float* __restrict__ part) {
  __shared__ float4 g2sh[1024];   // 16 KB: 128 rows x 8 float4 (a-chunk = 32)
  __shared__ float attsh[512];    // [nl][mloc] 2 KB
  float* psum = (float*)g2sh;     // 8 KB alias, used after hot loop

  const int tid = threadIdx.x;
  const int bid = blockIdx.x;
  const int q  = bid >> 9;          // slowest
  const int b  = (bid >> 7) & 3;
  const int ng = bid & 127;         // fastest
  const int n0 = ng * 4;
  const int mloc = tid & 127;
  const int nh = tid >> 7;

  const float4* __restrict__ W4 = (const float4*)Wa_w;
  const float* __restrict__ g1r0 = G1 + (size_t)(b * NN + n0 + nh * 2) * NA;

  float acc[2] = {0.f, 0.f};
  float sw = 0.f;

  for (int c = 0; c < 8; ++c) {
    const float4* __restrict__ src =
        (const float4*)(G2c + ((size_t)(b * 8 + c) * NN + q * 128) * 32);
    __syncthreads();
#pragma unroll
    for (int k = 0; k < 4; ++k) {
      int f = k * 256 + tid;            // 0..1023, fully coalesced 16KB
      int r = f >> 3, g = f & 7;
      g2sh[r * 8 + (g ^ (r & 7))] = src[f];
    }
    __syncthreads();
#pragma unroll
    for (int k4 = 0; k4 < 8; ++k4) {
      float4 v = g2sh[mloc * 8 + (k4 ^ (mloc & 7))];
      float g2v[4] = {v.x, v.y, v.z, v.w};
      float4 wq = W4[c * 8 + k4];
      float wv[4] = {wq.x, wq.y, wq.z, wq.w};
      sw += (wv[0] + wv[1]) + (wv[2] + wv[3]);
#pragma unroll
      for (int nl = 0; nl < 2; ++nl) {
        float4 g = *(const float4*)(g1r0 + nl * NA + c * 32 + k4 * 4);
        float g1v[4] = {g.x, g.y, g.z, g.w};
#pragma unroll
        for (int j = 0; j < 4; ++j) {
          float e = fexp2(g1v[j] + g2v[j]);        // exp2(C*(g1+g2+bg))
          acc[nl] = fmaf(wv[j], frcp(1.f + e), acc[nl]);
        }
      }
    }
  }

  // att scores (each (n,m) owned by exactly one thread -> no combine)
  {
    float bias = Wa_b[0] + ba[0];
#pragma unroll
    for (int nl = 0; nl < 2; ++nl) {
      float z = (sw + bias) - 2.f * acc[nl];
      attsh[(nh * 2 + nl) * 128 + mloc] = frcp(1.f + fexp2(-LOG2E * z));
    }
  }
  __syncthreads();

  // AV over this block's 128 m-rows: wave w -> m in [w*32, w*32+32)
  const int w = tid >> 6;
  const int l = tid & 63;
  float o0[4] = {0.f, 0.f, 0.f, 0.f};
  float o1[4] = {0.f, 0.f, 0.f, 0.f};
  const float* __restrict__ xb = xt + (size_t)(b * NN + q * 128 + w * 32) * ND;
  for (int mi = 0; mi < 32; ++mi) {
    const float* xr = xb + mi * ND;
    float xv0 = xr[l];
    float xv1 = xr[64 + (l & 31)];
#pragma unroll
    for (int nl = 0; nl < 4; ++nl) {
      float av = attsh[nl * 128 + w * 32 + mi];
      o0[nl] = fmaf(av, xv0, o0[nl]);
      o1[nl] = fmaf(av, xv1, o1[nl]);
    }
  }
  __syncthreads();   // g2sh reads long done; safe to alias as psum
#pragma unroll
  for (int nl = 0; nl < 4; ++nl) {
    psum[(w * 4 + nl) * 128 + l] = o0[nl];
    if (l < 32) psum[(w * 4 + nl) * 128 + 64 + l] = o1[nl];
  }
  __syncthreads();
#pragma unroll
  for (int it = 0; it < 2; ++it) {
    int idx = it * 256 + tid;
    int nl = idx >> 7;
    int d = idx & 127;
    if (d < ND) {
      float s = (psum[(0 + nl) * 128 + d] + psum[(4 + nl) * 128 + d]) +
                (psum[(8 + nl) * 128 + d] + psum[(12 + nl) * 128 + d]);
      // part[q][b][n][d], plain store (no atomics)
      part[((size_t)(q * NB + b) * NN + n0 + nl) * ND + d] = s;
    }
  }
}

// --- k_red: out = sum of 4 m-quarter partials. 196608 elems, coalesced.
__global__ __launch_bounds__(256) void k_red(const float* __restrict__ part,
                                             float* __restrict__ out) {
  int idx = blockIdx.x * 256 + threadIdx.x;   // 0 .. 4*512*96-1
  const size_t QS = (size_t)NB * NN * ND;
  out[idx] = (part[idx] + part[QS + idx]) + (part[2 * QS + idx] + part[3 * QS + idx]);
}

extern "C" void kernel_launch(void* const* d_in, const int* in_sizes, int n_in,
                              void* d_out, int out_size, void* d_ws, size_t ws_size,
                              hipStream_t stream) {
  const float* x    = (const float*)d_in[0];
  const float* Wg1  = (const float*)d_in[1];
  const float* Wg2  = (const float*)d_in[2];
  const float* bg   = (const float*)d_in[3];
  const float* Wa_w = (const float*)d_in[4];
  const float* Wa_b = (const float*)d_in[5];
  const float* ba   = (const float*)d_in[6];
  float* out = (float*)d_out;

  float* ws   = (float*)d_ws;
  float* G1   = ws;                 // 524288 floats
  float* G2c  = ws + 524288;        // 524288 (chunk-major)
  float* xtw  = ws + 1048576;       // 196608
  float* part = ws + 1245184;       // 786432 (4 quarter-partials)  total ~8.1 MB

  hipLaunchKernelGGL(k_proj, dim3(1024), dim3(256), 0, stream,
                     x, Wg1, Wg2, bg, G1, G2c, xtw);
  hipLaunchKernelGGL(k_main, dim3(2048), dim3(256), 0, stream,
                     G1, G2c, xtw, Wa_w, Wa_b, ba, part);
  hipLaunchKernelGGL(k_red, dim3(768), dim3(256), 0, stream, part, out);
}

// Round 8
// 187.249 us; speedup vs baseline: 1.4356x; 1.1377x over previous
//
#include <hip/hip_runtime.h>
#include <math.h>

#define NB 4
#define ND 96
#define NN 512
#define NA 256

static constexpr float C_TANH = 2.8853900817779268f; // 2*log2(e)
static constexpr float LOG2E  = 1.4426950408889634f;

__device__ __forceinline__ float fexp2(float x) {
#if __has_builtin(__builtin_amdgcn_exp2f)
  return __builtin_amdgcn_exp2f(x);
#else
  return exp2f(x);
#endif
}
__device__ __forceinline__ float frcp(float x) {
#if __has_builtin(__builtin_amdgcn_rcpf)
  return __builtin_amdgcn_rcpf(x);
#else
  return 1.0f / x;
#endif
}

// --- k_wt: blocks 0..191 transpose Wg1/Wg2 -> [d][a]; block 192: S0 = sum(Wa_w)+Wa_b+ba.
__global__ __launch_bounds__(256) void k_wt(const float* __restrict__ Wg1,
                                            const float* __restrict__ Wg2,
                                            const float* __restrict__ Wa_w,
                                            const float* __restrict__ Wa_b,
                                            const float* __restrict__ ba,
                                            float* __restrict__ W1t,
                                            float* __restrict__ W2t,
                                            float* __restrict__ S0) {
  if (blockIdx.x == 192) {
    __shared__ float red[256];
    int t = threadIdx.x;
    red[t] = Wa_w[t];
    __syncthreads();
    for (int s = 128; s > 0; s >>= 1) {
      if (t < s) red[t] += red[t + s];
      __syncthreads();
    }
    if (t == 0) S0[0] = red[0] + Wa_b[0] + ba[0];
    return;
  }
  int idx = blockIdx.x * 256 + threadIdx.x;  // 0 .. 2*96*256-1
  int mat = idx / (ND * NA);
  int rem = idx - mat * (ND * NA);
  int d = rem >> 8;
  int a = rem & 255;
  (mat ? W2t : W1t)[d * NA + a] = (mat ? Wg2 : Wg1)[a * ND + d];
}

// --- k_proj: G1[b,n,a] = C*(x.Wg1 + bg) row-major, G2 chunk-major, xt = x^T.
// Block = (b, 8 n's), thread = a. Grid 256. Weights read COALESCED via W1t/W2t
// (lane = a), amortized over 8 n's.
__global__ __launch_bounds__(256, 4) void k_proj(const float* __restrict__ x,
                                                 const float* __restrict__ W1t,
                                                 const float* __restrict__ W2t,
                                                 const float* __restrict__ bg,
                                                 float* __restrict__ G1,
                                                 float* __restrict__ G2c,
                                                 float* __restrict__ xt) {
  __shared__ float xsh[ND][8];   // xsh[d][j] = x[b, d, n0+j]
  const int tid = threadIdx.x;
  const int b = blockIdx.x >> 6;
  const int n0 = (blockIdx.x & 63) * 8;

#pragma unroll
  for (int it = 0; it < 3; ++it) {
    int idx = it * 256 + tid;        // 768 floats
    int d = idx >> 3, j = idx & 7;
    float v = x[(size_t)(b * ND + d) * NN + n0 + j];
    xsh[d][j] = v;
    xt[(size_t)(b * NN + n0 + j) * ND + d] = v;
  }
  __syncthreads();

  const int a = tid;
  const float bgv = bg[a];
  float acc1[8], acc2[8];
#pragma unroll
  for (int j = 0; j < 8; ++j) { acc1[j] = bgv; acc2[j] = 0.f; }

#pragma unroll 2
  for (int d = 0; d < ND; ++d) {
    float w1 = W1t[d * NA + a];      // coalesced
    float w2 = W2t[d * NA + a];
    float4 xa = *(const float4*)&xsh[d][0];   // broadcast
    float4 xb = *(const float4*)&xsh[d][4];
    float xv[8] = {xa.x, xa.y, xa.z, xa.w, xb.x, xb.y, xb.z, xb.w};
#pragma unroll
    for (int j = 0; j < 8; ++j) {
      acc1[j] = fmaf(w1, xv[j], acc1[j]);
      acc2[j] = fmaf(w2, xv[j], acc2[j]);
    }
  }
  const int c = a >> 5, al = a & 31;
#pragma unroll
  for (int j = 0; j < 8; ++j) {
    G1[(size_t)(b * NN + n0 + j) * NA + a] = C_TANH * acc1[j];
    G2c[((size_t)(b * 8 + c) * NN + n0 + j) * 32 + al] = C_TANH * acc2[j];
  }
}

// --- k_main: fused pairwise-tanh attention + AV (partial over m-quarter).
// Grid 2048: bid = q*512 + b*128 + ng (q slowest -> concurrent blocks share q,b).
// ALL hot-loop operands live in LDS (G2 staged 16KB/chunk, G1 slice 4KB, W 1KB)
// -> ~30 live VGPRs, structurally spill-free (r5/r6 regressions were scratch
// spill: WRITE_SIZE 354/142MB vs 3MB payload).
__global__ __launch_bounds__(256, 4) void k_main(const float* __restrict__ G1,
                                                 const float* __restrict__ G2c,
                                                 const float* __restrict__ xt,
                                                 const float* __restrict__ Wa_w,
                                                 const float* __restrict__ S0p,
                                                 float* __restrict__ part) {
  __shared__ float4 g2sh[1024];   // 16 KB: 128 rows x 8 float4, swizzled
  __shared__ float4 g1s4[256];    // 4 KB: 4 n x 64 float4 (256 a)
  __shared__ float4 wsh4[64];     // 1 KB
  __shared__ float attsh[512];    // 2 KB
  float* psum = (float*)g2sh;     // alias, used after hot loop

  const int tid = threadIdx.x;
  const int bid = blockIdx.x;
  const int q  = bid >> 9;
  const int b  = (bid >> 7) & 3;
  const int ng = bid & 127;
  const int n0 = ng * 4;
  const int mloc = tid & 127;
  const int nh = tid >> 7;
  const float S0 = S0p[0];

  // prologue: G1 block-slice + W into LDS (coalesced), visible after first sync
  g1s4[tid] = *((const float4*)(G1 + (size_t)(b * NN + n0) * NA) + tid);
  if (tid < 64) wsh4[tid] = ((const float4*)Wa_w)[tid];

  float acc0 = 0.f, acc1 = 0.f;

#pragma unroll 1
  for (int c = 0; c < 8; ++c) {
    const float4* __restrict__ src =
        (const float4*)(G2c + ((size_t)(b * 8 + c) * NN + q * 128) * 32);
    __syncthreads();
#pragma unroll
    for (int k = 0; k < 4; ++k) {
      int f = k * 256 + tid;            // 0..1023, fully coalesced 16KB
      int r = f >> 3, g = f & 7;
      g2sh[r * 8 + (g ^ (r & 7))] = src[f];
    }
    __syncthreads();
#pragma unroll
    for (int k4 = 0; k4 < 8; ++k4) {
      float4 v = g2sh[mloc * 8 + (k4 ^ (mloc & 7))];   // per-lane
      float4 wq = wsh4[c * 8 + k4];                     // broadcast
      float4 ga = g1s4[(nh * 2 + 0) * 64 + c * 8 + k4]; // broadcast
      float4 gb = g1s4[(nh * 2 + 1) * 64 + c * 8 + k4]; // broadcast
      float g2v[4] = {v.x, v.y, v.z, v.w};
      float wv[4]  = {wq.x, wq.y, wq.z, wq.w};
      float gav[4] = {ga.x, ga.y, ga.z, ga.w};
      float gbv[4] = {gb.x, gb.y, gb.z, gb.w};
#pragma unroll
      for (int j = 0; j < 4; ++j) {
        float ea = fexp2(gav[j] + g2v[j]);   // exp2(C*(g1+g2+bg))
        acc0 = fmaf(wv[j], frcp(1.f + ea), acc0);
        float eb = fexp2(gbv[j] + g2v[j]);
        acc1 = fmaf(wv[j], frcp(1.f + eb), acc1);
      }
    }
  }

  // att = sigmoid(S0 - 2*acc)
  {
    float z0 = S0 - 2.f * acc0;
    float z1 = S0 - 2.f * acc1;
    attsh[(nh * 2 + 0) * 128 + mloc] = frcp(1.f + fexp2(-LOG2E * z0));
    attsh[(nh * 2 + 1) * 128 + mloc] = frcp(1.f + fexp2(-LOG2E * z1));
  }
  __syncthreads();

  // AV over this block's 128 m-rows: wave w -> m in [w*32, w*32+32)
  const int w = tid >> 6;
  const int l = tid & 63;
  float o0[4] = {0.f, 0.f, 0.f, 0.f};
  float o1[4] = {0.f, 0.f, 0.f, 0.f};
  const float* __restrict__ xb = xt + (size_t)(b * NN + q * 128 + w * 32) * ND;
  for (int mi = 0; mi < 32; ++mi) {
    const float* xr = xb + mi * ND;
    float xv0 = xr[l];
    float xv1 = xr[64 + (l & 31)];
#pragma unroll
    for (int nl = 0; nl < 4; ++nl) {
      float av = attsh[nl * 128 + w * 32 + mi];
      o0[nl] = fmaf(av, xv0, o0[nl]);
      o1[nl] = fmaf(av, xv1, o1[nl]);
    }
  }
  __syncthreads();   // g2sh reads done; safe to alias as psum
#pragma unroll
  for (int nl = 0; nl < 4; ++nl) {
    psum[(w * 4 + nl) * 128 + l] = o0[nl];
    if (l < 32) psum[(w * 4 + nl) * 128 + 64 + l] = o1[nl];
  }
  __syncthreads();
#pragma unroll
  for (int it = 0; it < 2; ++it) {
    int idx = it * 256 + tid;
    int nl = idx >> 7;
    int d = idx & 127;
    if (d < ND) {
      float s = (psum[(0 + nl) * 128 + d] + psum[(4 + nl) * 128 + d]) +
                (psum[(8 + nl) * 128 + d] + psum[(12 + nl) * 128 + d]);
      part[((size_t)(q * NB + b) * NN + n0 + nl) * ND + d] = s;   // no atomics
    }
  }
}

// --- k_red: out = sum of 4 m-quarter partials. Coalesced.
__global__ __launch_bounds__(256) void k_red(const float* __restrict__ part,
                                             float* __restrict__ out) {
  int idx = blockIdx.x * 256 + threadIdx.x;   // 0 .. 4*512*96-1
  const size_t QS = (size_t)NB * NN * ND;
  out[idx] = (part[idx] + part[QS + idx]) + (part[2 * QS + idx] + part[3 * QS + idx]);
}

extern "C" void kernel_launch(void* const* d_in, const int* in_sizes, int n_in,
                              void* d_out, int out_size, void* d_ws, size_t ws_size,
                              hipStream_t stream) {
  const float* x    = (const float*)d_in[0];
  const float* Wg1  = (const float*)d_in[1];
  const float* Wg2  = (const float*)d_in[2];
  const float* bg   = (const float*)d_in[3];
  const float* Wa_w = (const float*)d_in[4];
  const float* Wa_b = (const float*)d_in[5];
  const float* ba   = (const float*)d_in[6];
  float* out = (float*)d_out;

  float* ws   = (float*)d_ws;
  float* G1   = ws;                 // 524288 floats
  float* G2c  = ws + 524288;        // 524288 (chunk-major)
  float* xtw  = ws + 1048576;       // 196608
  float* W1t  = ws + 1245184;       // 24576
  float* W2t  = ws + 1269760;       // 24576
  float* S0   = ws + 1294336;       // 256 (padded)
  float* part = ws + 1294592;       // 786432   total ~8.3 MB

  hipLaunchKernelGGL(k_wt,   dim3(193), dim3(256), 0, stream,
                     Wg1, Wg2, Wa_w, Wa_b, ba, W1t, W2t, S0);
  hipLaunchKernelGGL(k_proj, dim3(256), dim3(256), 0, stream,
                     x, W1t, W2t, bg, G1, G2c, xtw);
  hipLaunchKernelGGL(k_main, dim3(2048), dim3(256), 0, stream,
                     G1, G2c, xtw, Wa_w, S0, part);
  hipLaunchKernelGGL(k_red,  dim3(768), dim3(256), 0, stream, part, out);
}